// Round 18
// baseline (278.709 us; speedup 1.0000x reference)
//
#include <hip/hip_runtime.h>
#include <hip/hip_bf16.h>

typedef __attribute__((ext_vector_type(8))) _Float16 half8_t;
typedef __attribute__((ext_vector_type(4))) _Float16 half4_t;
typedef __attribute__((ext_vector_type(4))) float float4_t;

#define D_DIM 768
#define S_DIM 4096
#define B_DIM 4
#define M_DIM (B_DIM * S_DIM)  // 16384
#define SD ((size_t)S_DIM * D_DIM)

#define GLOAD_LDS16(g, s)                                      \
  __builtin_amdgcn_global_load_lds(                            \
      (const __attribute__((address_space(1))) void*)(g),      \
      (__attribute__((address_space(3))) void*)(s), 16, 0, 0)

__device__ __forceinline__ float4_t mfma16(half8_t a, half8_t b, float4_t c) {
  return __builtin_amdgcn_mfma_f32_16x16x32_f16(a, b, c, 0, 0, 0);
}

// ---------------- fused pre-pass: x -> fp16 AND W -> WT (one dispatch) ----------
__global__ __launch_bounds__(256) void prep_kernel(const float* __restrict__ x,
                                                   const float* __restrict__ W0,
                                                   const float* __restrict__ W1,
                                                   const float* __restrict__ W2,
                                                   _Float16* __restrict__ xh,
                                                   _Float16* __restrict__ WT) {
  __shared__ _Float16 tile[64][68];
  const int bid = blockIdx.x;
  if (bid < 12288) {
    int i = (bid * 256 + threadIdx.x) * 4;
    float4 v = *(const float4*)(x + i);
    half4_t o;
    o.x = (_Float16)v.x; o.y = (_Float16)v.y; o.z = (_Float16)v.z; o.w = (_Float16)v.w;
    *(half4_t*)(xh + i) = o;
  } else {
    int t = bid - 12288;
    int z = t / 144;
    int r = t % 144;
    int kx = r / 12, ny = r % 12;
    const float* W = (z == 0) ? W0 : (z == 1) ? W1 : W2;
    _Float16* o = WT + (size_t)z * D_DIM * D_DIM;
    int k0 = kx * 64, n0 = ny * 64;
#pragma unroll
    for (int i = 0; i < 16; ++i) {
      int idx = threadIdx.x + i * 256;
      int rr = idx >> 6, cc = idx & 63;
      tile[rr][cc] = (_Float16)W[(size_t)(k0 + rr) * D_DIM + n0 + cc];
    }
    __syncthreads();
#pragma unroll
    for (int i = 0; i < 16; ++i) {
      int idx = threadIdx.x + i * 256;
      int rr = idx >> 6, cc = idx & 63;
      o[(size_t)(n0 + rr) * D_DIM + k0 + cc] = tile[cc][rr];
    }
  }
}

// ====== 8-phase 256^2 core (m201 template): BK=64, 8 waves, 2 dbuf = 128 KB ======
// Per tile t (buf t&1), 4 phases: {ds_reads (q0: 8 B + 4 A; else 4 A) -> stage ONE
// 16KB half-group -> barrier -> (compiler lgkmcnt) -> 16 MFMA under setprio ->
// barrier}. Stage schedule: q0: AHY(t+1); q1: BH0(t+2); q2: BH1(t+2); q3: AHX(t+2)
// — each target region provably dead (B dies after q0's barrier pair; A-half-X
// [rows 0-63,128-191] after q2; A-half-Y after q3). Counted vmcnt(6) ONCE per tile
// (before q3's closing barrier) = template's 3-half-tiles-in-flight; vmcnt(0) only
// in the tail. Granule swizzle u' = u^(row&7) (0-conflict, rounds 12-17).
template <bool SWAP>
__device__ __forceinline__ void core256f(const _Float16* __restrict__ Ag,
                                         const _Float16* __restrict__ Bg,
                                         int lda, int ldb, int nt,
                                         char* lds, float4_t (&acc)[8][4]) {
  const int tid = threadIdx.x;
  const int w = tid >> 6, l = tid & 63;
  const int wm = w >> 2, wn = w & 3;
  const int l15 = l & 15, l4 = l >> 4;

  // staging precompute: each half-group = 16 KB = 2 wave-insts; g = i*512+tid
  int srcB0[2], srcB1[2], srcAX[2], srcAY[2], dstLin[2];
#pragma unroll
  for (int i = 0; i < 2; ++i) {
    int g = i * 512 + tid;
    int r = g >> 3, u = g & 7;
    int usw = (u ^ (r & 7)) * 8;
    srcB0[i] = r * ldb + usw;
    srcB1[i] = (r + 128) * ldb + usw;
    srcAX[i] = (r + (i ? 64 : 0)) * lda + usw;        // rows 0-63 | 128-191
    srcAY[i] = (r + 64 + (i ? 64 : 0)) * lda + usw;   // rows 64-127 | 192-255
    dstLin[i] = (i * 512 + (tid & ~63)) * 16;
  }

#define STG_B0(t)                                                       \
  do {                                                                  \
    char* bb = lds + ((t) & 1) * 65536 + 32768;                         \
    const _Float16* s = Bg + (size_t)(t) * 64;                          \
    GLOAD_LDS16(s + srcB0[0], bb + dstLin[0]);                          \
    GLOAD_LDS16(s + srcB0[1], bb + dstLin[1]);                          \
  } while (0)
#define STG_B1(t)                                                       \
  do {                                                                  \
    char* bb = lds + ((t) & 1) * 65536 + 49152;                         \
    const _Float16* s = Bg + (size_t)(t) * 64;                          \
    GLOAD_LDS16(s + srcB1[0], bb + dstLin[0]);                          \
    GLOAD_LDS16(s + srcB1[1], bb + dstLin[1]);                          \
  } while (0)
#define STG_AX(t)                                                       \
  do {                                                                  \
    char* bb = lds + ((t) & 1) * 65536;                                 \
    const _Float16* s = Ag + (size_t)(t) * 64;                          \
    GLOAD_LDS16(s + srcAX[0], bb + dstLin[0]);                          \
    GLOAD_LDS16(s + srcAX[1], bb + dstLin[1] + 8192);                   \
  } while (0)
#define STG_AY(t)                                                       \
  do {                                                                  \
    char* bb = lds + ((t) & 1) * 65536;                                 \
    const _Float16* s = Ag + (size_t)(t) * 64;                          \
    GLOAD_LDS16(s + srcAY[0], bb + dstLin[0] + 8192);                   \
    GLOAD_LDS16(s + srcAY[1], bb + dstLin[1] + 16384);                  \
  } while (0)

  // frag read bases (row&7 == l15&7 for all frags -> immediate-friendly)
  const int a7 = l15 & 7;
  int aBase[2], bBase[2];
#pragma unroll
  for (int ks = 0; ks < 2; ++ks) {
    int kk = ((ks * 4 + l4) ^ a7) * 16;
    aBase[ks] = wm * 16384 + l15 * 128 + kk;
    bBase[ks] = 32768 + wn * 8192 + l15 * 128 + kk;
  }

  // prologue: tile 0 fully + tile 1 minus AHY (AHY(1) staged at q0 of t=0)
  STG_B0(0); STG_B1(0); STG_AX(0); STG_AY(0);
  if (nt > 1) {
    STG_B0(1); STG_B1(1); STG_AX(1);
    asm volatile("s_waitcnt vmcnt(6)" ::: "memory");  // tile 0 landed
  } else {
    asm volatile("s_waitcnt vmcnt(0)" ::: "memory");
  }
  __builtin_amdgcn_s_barrier();

  half8_t bf[2][4];

  auto do_mfma = [&](int mh, int ks, half8_t (&af)[4]) {
    __builtin_amdgcn_s_setprio(1);
#pragma unroll
    for (int i = 0; i < 4; ++i)
#pragma unroll
      for (int n = 0; n < 4; ++n) {
        if (SWAP)
          acc[mh * 4 + i][n] = mfma16(bf[ks][n], af[i], acc[mh * 4 + i][n]);
        else
          acc[mh * 4 + i][n] = mfma16(af[i], bf[ks][n], acc[mh * 4 + i][n]);
      }
    __builtin_amdgcn_s_setprio(0);
  };

#pragma unroll 1
  for (int t = 0; t < nt; ++t) {
    const char* Lb = lds + (t & 1) * 65536;
    // ---- q0: mh0,ks0; reads: all B (8) + A (4); stage AHY(t+1) ----
    {
      half8_t af[4];
#pragma unroll
      for (int ks = 0; ks < 2; ++ks)
#pragma unroll
        for (int n = 0; n < 4; ++n)
          bf[ks][n] = *(const half8_t*)(Lb + bBase[ks] + n * 2048);
#pragma unroll
      for (int i = 0; i < 4; ++i)
        af[i] = *(const half8_t*)(Lb + aBase[0] + i * 2048);
      if (t + 1 < nt) STG_AY(t + 1);
      __builtin_amdgcn_sched_barrier(0);
      __builtin_amdgcn_s_barrier();
      __builtin_amdgcn_sched_barrier(0);
      do_mfma(0, 0, af);
      __builtin_amdgcn_sched_barrier(0);
      __builtin_amdgcn_s_barrier();
    }
    // ---- q1: mh1,ks0; stage BH0(t+2) ----
    {
      half8_t af[4];
#pragma unroll
      for (int i = 0; i < 4; ++i)
        af[i] = *(const half8_t*)(Lb + aBase[0] + (4 + i) * 2048);
      if (t + 2 < nt) STG_B0(t + 2);
      __builtin_amdgcn_sched_barrier(0);
      __builtin_amdgcn_s_barrier();
      __builtin_amdgcn_sched_barrier(0);
      do_mfma(1, 0, af);
      __builtin_amdgcn_sched_barrier(0);
      __builtin_amdgcn_s_barrier();
    }
    // ---- q2: mh0,ks1; stage BH1(t+2) ----
    {
      half8_t af[4];
#pragma unroll
      for (int i = 0; i < 4; ++i)
        af[i] = *(const half8_t*)(Lb + aBase[1] + i * 2048);
      if (t + 2 < nt) STG_B1(t + 2);
      __builtin_amdgcn_sched_barrier(0);
      __builtin_amdgcn_s_barrier();
      __builtin_amdgcn_sched_barrier(0);
      do_mfma(0, 1, af);
      __builtin_amdgcn_sched_barrier(0);
      __builtin_amdgcn_s_barrier();
    }
    // ---- q3: mh1,ks1; stage AHX(t+2); counted vmcnt before closing barrier ----
    {
      half8_t af[4];
#pragma unroll
      for (int i = 0; i < 4; ++i)
        af[i] = *(const half8_t*)(Lb + aBase[1] + (4 + i) * 2048);
      if (t + 2 < nt) STG_AX(t + 2);
      __builtin_amdgcn_sched_barrier(0);
      __builtin_amdgcn_s_barrier();
      __builtin_amdgcn_sched_barrier(0);
      do_mfma(1, 1, af);
      __builtin_amdgcn_sched_barrier(0);
      if (t + 2 < nt)
        asm volatile("s_waitcnt vmcnt(6)" ::: "memory");   // tile t+1 landed
      else if (t + 1 < nt)
        asm volatile("s_waitcnt vmcnt(0)" ::: "memory");
      __builtin_amdgcn_sched_barrier(0);
      __builtin_amdgcn_s_barrier();
    }
  }
#undef STG_B0
#undef STG_B1
#undef STG_AX
#undef STG_AY
}

// ============ m97-style 4-wave GEMM core: BM=BN=128, BK=64 (gemm2) ============
template <bool SWAP>
__device__ __forceinline__ void core128(const _Float16* __restrict__ Ag,
                                        const _Float16* __restrict__ Bg,
                                        int lda, int ldb, int nt,
                                        char* lds, float4_t (&acc)[4][4]) {
  const int tid = threadIdx.x;
  const int w = tid >> 6, l = tid & 63;
  const int wr = w >> 1, wc = w & 1;
  const int l15 = l & 15, l4 = l >> 4;

  int sA[4], sB[4], sDst[4];
#pragma unroll
  for (int i = 0; i < 4; ++i) {
    int L = i * 256 + tid;
    int row = L >> 3, u = L & 7;
    int usw = u ^ (row & 7);
    sA[i] = row * lda + usw * 8;
    sB[i] = row * ldb + usw * 8;
    sDst[i] = (i * 256 + (tid & ~63)) * 16;
  }

  int aOff[2][4], bOff[2][4];
#pragma unroll
  for (int ks = 0; ks < 2; ++ks) {
#pragma unroll
    for (int i = 0; i < 4; ++i) {
      int ar = wr * 64 + i * 16 + l15;
      aOff[ks][i] = ar * 128 + (((ks * 4 + l4) ^ (ar & 7)) * 16);
      int br = wc * 64 + i * 16 + l15;
      bOff[ks][i] = 16384 + br * 128 + (((ks * 4 + l4) ^ (br & 7)) * 16);
    }
  }

#pragma unroll 1
  for (int kt = 0; kt < nt; ++kt) {
#pragma unroll
    for (int i = 0; i < 4; ++i)
      GLOAD_LDS16(Ag + (size_t)kt * 64 + sA[i], lds + sDst[i]);
#pragma unroll
    for (int i = 0; i < 4; ++i)
      GLOAD_LDS16(Bg + (size_t)kt * 64 + sB[i], lds + 16384 + sDst[i]);
    __syncthreads();
#pragma unroll
    for (int ks = 0; ks < 2; ++ks) {
      half8_t af[4], bf[4];
#pragma unroll
      for (int ni = 0; ni < 4; ++ni) bf[ni] = *(const half8_t*)(lds + bOff[ks][ni]);
#pragma unroll
      for (int mi = 0; mi < 4; ++mi) af[mi] = *(const half8_t*)(lds + aOff[ks][mi]);
      __builtin_amdgcn_s_setprio(1);
#pragma unroll
      for (int mi = 0; mi < 4; ++mi)
#pragma unroll
        for (int ni = 0; ni < 4; ++ni) {
          if (SWAP)
            acc[mi][ni] = mfma16(bf[ni], af[mi], acc[mi][ni]);
          else
            acc[mi][ni] = mfma16(af[mi], bf[ni], acc[mi][ni]);
        }
      __builtin_amdgcn_s_setprio(0);
    }
    __syncthreads();
  }
}

// ---------------- proj (256^2 8-phase): q,k normal; v direct-transposed ----------
// grid 576 = 8 x 72 XCD-bijective; wid = rg2*18 + z*6 + cb*2 + r01 (R16-verified).
__global__ __launch_bounds__(512, 2) void proj8_kernel(const _Float16* __restrict__ xh,
                                                       const _Float16* __restrict__ WT,
                                                       _Float16* __restrict__ qkv,
                                                       _Float16* __restrict__ vt) {
  __shared__ __align__(16) char lds[131072];
  const int bid = blockIdx.x;
  const int wid = (bid & 7) * 72 + (bid >> 3);
  const int rg2 = wid / 18;
  const int rem = wid % 18;
  const int z = rem / 6;
  const int cb = (rem % 6) >> 1;
  const int rbg = rg2 * 2 + (rem & 1);

  const _Float16* Ag = xh + (size_t)rbg * 256 * D_DIM;
  const _Float16* Bg = WT + (size_t)z * D_DIM * D_DIM + (size_t)cb * 256 * D_DIM;
  float4_t acc[8][4];
#pragma unroll
  for (int a = 0; a < 8; ++a)
#pragma unroll
    for (int b = 0; b < 4; ++b) acc[a][b] = (float4_t){0.f, 0.f, 0.f, 0.f};

  const int tid = threadIdx.x;
  const int w = tid >> 6, l = tid & 63;
  const int wr = w >> 2, wc = w & 3;
  const int l15 = l & 15, l4 = l >> 4;

  if (z < 2) {
    core256f<false>(Ag, Bg, D_DIM, D_DIM, 12, lds, acc);
    _Float16* C = qkv + (size_t)z * M_DIM * D_DIM;
#pragma unroll
    for (int mi = 0; mi < 8; ++mi)
#pragma unroll
      for (int ni = 0; ni < 4; ++ni) {
        int col = cb * 256 + wc * 64 + ni * 16 + l15;
#pragma unroll
        for (int j = 0; j < 4; ++j) {
          int row = rbg * 256 + wr * 128 + mi * 16 + l4 * 4 + j;
          C[(size_t)row * D_DIM + col] = (_Float16)acc[mi][ni][j];
        }
      }
  } else {
    core256f<true>(Ag, Bg, D_DIM, D_DIM, 12, lds, acc);
#pragma unroll
    for (int mi = 0; mi < 8; ++mi) {
      int scol = rbg * 256 + wr * 128 + mi * 16 + l15;
      int bb = scol >> 12;
      int sl = scol & 4095;
      _Float16* vtb = vt + (size_t)bb * SD;
#pragma unroll
      for (int ni = 0; ni < 4; ++ni) {
#pragma unroll
        for (int j = 0; j < 4; ++j) {
          int drow = cb * 256 + wc * 64 + ni * 16 + l4 * 4 + j;
          vtb[(size_t)drow * S_DIM + sl] = (_Float16)acc[mi][ni][j];
        }
      }
    }
  }
}

// ---------------- gemm1 (256^2 8-phase): P = exp(scale*QK^T - 4) causal ----------
// grid 544 = 8 x 68; 136 triangle blocks per z, 4x4-supertiled (R16-verified).
// rp slots cb*4+wc; rows in masked half write zeros (gemm2 skips them).
__global__ __launch_bounds__(512, 2) void gemm1_8_kernel(const _Float16* __restrict__ Q,
                                                         const _Float16* __restrict__ K,
                                                         _Float16* __restrict__ P,
                                                         float* __restrict__ rp) {
  __shared__ __align__(16) char lds[131072];
  const float SCALE = 0.036084391824351615f;  // 1/sqrt(768)
  const int bid = blockIdx.x;
  const int wid = (bid & 7) * 68 + (bid >> 3);
  const int z = wid / 136;
  const int t = wid % 136;
  int g, base;
  if (t < 10) { g = 0; base = 0; }
  else if (t < 36) { g = 1; base = 10; }
  else if (t < 78) { g = 2; base = 36; }
  else { g = 3; base = 78; }
  int r = t - base;
  int rbg, cb;
  if (r < 16 * g) {
    int cbg = r >> 4, wi = r & 15;
    rbg = 4 * g + (wi >> 2);
    cb = 4 * cbg + (wi & 3);
  } else {
    int r2 = r - 16 * g;
    const int ri[10] = {0, 1, 1, 2, 2, 2, 3, 3, 3, 3};
    const int rj[10] = {0, 0, 1, 0, 1, 2, 0, 1, 2, 3};
    rbg = 4 * g + ri[r2];
    cb = 4 * g + rj[r2];
  }

  const _Float16* Ag = Q + (size_t)z * SD + (size_t)rbg * 256 * D_DIM;
  const _Float16* Bg = K + (size_t)z * SD + (size_t)cb * 256 * D_DIM;
  float4_t acc[8][4];
#pragma unroll
  for (int a = 0; a < 8; ++a)
#pragma unroll
    for (int b = 0; b < 4; ++b) acc[a][b] = (float4_t){0.f, 0.f, 0.f, 0.f};
  core256f<false>(Ag, Bg, D_DIM, D_DIM, 12, lds, acc);

  const int tid = threadIdx.x;
  const int w = tid >> 6, l = tid & 63;
  const int wr = w >> 2, wc = w & 3;
  const int l15 = l & 15, l4 = l >> 4;
  _Float16* Pz = P + (size_t)z * S_DIM * S_DIM;
  float* rpz = rp + (size_t)z * S_DIM * 64;
#pragma unroll
  for (int mi = 0; mi < 8; ++mi) {
#pragma unroll
    for (int j = 0; j < 4; ++j) {
      int row = rbg * 256 + wr * 128 + mi * 16 + l4 * 4 + j;
      float rs = 0.f;
#pragma unroll
      for (int ni = 0; ni < 4; ++ni) {
        int col = cb * 256 + wc * 64 + ni * 16 + l15;
        float v = (col <= row) ? __expf(acc[mi][ni][j] * SCALE - 4.0f) : 0.f;
        _Float16 ph = (_Float16)v;
        Pz[(size_t)row * S_DIM + col] = ph;
        rs += (float)ph;
      }
#pragma unroll
      for (int d = 1; d < 16; d <<= 1) rs += __shfl_xor(rs, d);
      if (l15 == 0) rpz[(size_t)row * 64 + cb * 4 + wc] = rs;
    }
  }
}

// ---------------- gemm2: out = (P @ VT^T)/rsum — 768 single-job blocks ------
// (round-17 kernel, unchanged; in-kernel rsum over rp partials)
__global__ __launch_bounds__(256) void gemm2_8_kernel(const _Float16* __restrict__ P,
                                                      const _Float16* __restrict__ VT,
                                                      float* __restrict__ outp,
                                                      const float* __restrict__ rp) {
  __shared__ __align__(16) char lds[32768];
  __shared__ float rsm[128];
  const int bid = blockIdx.x;
  const int g = bid / 24;
  const int q = bid % 24;
  const int rbg = 31 - g;
  const int xcd = q & 7;
  const int slot = q >> 3;
  const int z = xcd >> 1;
  const int by = (xcd & 1) * 3 + slot;
  const int nt = 2 * (rbg + 1);

  const _Float16* Ag = P + (size_t)z * S_DIM * S_DIM + (size_t)rbg * 128 * S_DIM;
  const _Float16* Bg = VT + (size_t)z * SD + (size_t)by * 128 * S_DIM;
  float4_t acc[4][4];
#pragma unroll
  for (int a = 0; a < 4; ++a)
#pragma unroll
    for (int b = 0; b < 4; ++b) acc[a][b] = (float4_t){0.f, 0.f, 0.f, 0.f};
  core128<false>(Ag, Bg, S_DIM, S_DIM, nt, lds, acc);

  const int tid = threadIdx.x;
  if (tid < 128) {
    const float* p = rp + ((size_t)z * S_DIM + (size_t)rbg * 128 + tid) * 64;
    float s = 0.f;
    for (int i = 0; i < nt; ++i) s += p[i];
    rsm[tid] = 1.0f / s;
  }
  __syncthreads();

  const int w = tid >> 6, l = tid & 63;
  const int wr = w >> 1, wc = w & 1;
  const int l15 = l & 15, l4 = l >> 4;
#pragma unroll
  for (int mi = 0; mi < 4; ++mi) {
#pragma unroll
    for (int j = 0; j < 4; ++j) {
      int lrow = wr * 64 + mi * 16 + l4 * 4 + j;
      int row = rbg * 128 + lrow;
      float rinv = rsm[lrow];
#pragma unroll
      for (int ni = 0; ni < 4; ++ni) {
        int col = by * 128 + wc * 64 + ni * 16 + l15;
        outp[(size_t)z * SD + (size_t)row * D_DIM + col] = acc[mi][ni][j] * rinv;
      }
    }
  }
}

extern "C" void kernel_launch(void* const* d_in, const int* in_sizes, int n_in,
                              void* d_out, int out_size, void* d_ws, size_t ws_size,
                              hipStream_t stream) {
  const float* x = (const float*)d_in[0];
  const float* Wq = (const float*)d_in[1];
  const float* Wk = (const float*)d_in[2];
  const float* Wv = (const float*)d_in[3];
  float* out = (float*)d_out;
  char* ws = (char*)d_ws;

  const size_t XH_B = (size_t)M_DIM * D_DIM * 2;      // 25,165,824
  const size_t QKV_B = 3 * XH_B;                      // 75,497,472
  const size_t VT_B = XH_B;                           // 25,165,824
  const size_t WT_B = (size_t)3 * D_DIM * D_DIM * 2;  // 3,538,944
  const size_t BASE_END = XH_B + QKV_B + VT_B + WT_B; // 129,368,064

  _Float16* xh = (_Float16*)ws;
  _Float16* qkv = (_Float16*)(ws + XH_B);
  _Float16* Q = qkv;
  _Float16* K = qkv + (size_t)M_DIM * D_DIM;
  _Float16* vt = (_Float16*)(ws + XH_B + QKV_B);
  _Float16* wt = (_Float16*)(ws + XH_B + QKV_B + VT_B);

  // tier-A layout (rounds 4-17 prove ws_size >= 267,845,632)
  float* rp = (float*)(ws + BASE_END);                        // 4 MB
  _Float16* P = (_Float16*)(ws + BASE_END + (size_t)4259840); // 134 MB

  prep_kernel<<<dim3(12720), dim3(256), 0, stream>>>(x, Wq, Wk, Wv, xh, wt);
  proj8_kernel<<<dim3(576), dim3(512), 0, stream>>>(xh, wt, qkv, vt);
  gemm1_8_kernel<<<dim3(544), dim3(512), 0, stream>>>(Q, K, P, rp);
  gemm2_8_kernel<<<dim3(768), dim3(256), 0, stream>>>(P, vt, out, rp);
}

// Round 19
// 263.350 us; speedup vs baseline: 1.0583x; 1.0583x over previous
//
#include <hip/hip_runtime.h>
#include <hip/hip_bf16.h>

typedef __attribute__((ext_vector_type(8))) _Float16 half8_t;
typedef __attribute__((ext_vector_type(4))) _Float16 half4_t;
typedef __attribute__((ext_vector_type(4))) float float4_t;

#define D_DIM 768
#define S_DIM 4096
#define B_DIM 4
#define M_DIM (B_DIM * S_DIM)  // 16384
#define SD ((size_t)S_DIM * D_DIM)

#define GLOAD_LDS16(g, s)                                      \
  __builtin_amdgcn_global_load_lds(                            \
      (const __attribute__((address_space(1))) void*)(g),      \
      (__attribute__((address_space(3))) void*)(s), 16, 0, 0)

__device__ __forceinline__ float4_t mfma16(half8_t a, half8_t b, float4_t c) {
  return __builtin_amdgcn_mfma_f32_16x16x32_f16(a, b, c, 0, 0, 0);
}

// ---------------- fused pre-pass: x -> fp16 AND W -> WT (one dispatch) ----------
// blocks [0, 12288): cvt_x (4 floats/thread). blocks [12288, 12720): W transpose.
__global__ __launch_bounds__(256) void prep_kernel(const float* __restrict__ x,
                                                   const float* __restrict__ W0,
                                                   const float* __restrict__ W1,
                                                   const float* __restrict__ W2,
                                                   _Float16* __restrict__ xh,
                                                   _Float16* __restrict__ WT) {
  __shared__ _Float16 tile[64][68];
  const int bid = blockIdx.x;
  if (bid < 12288) {
    int i = (bid * 256 + threadIdx.x) * 4;
    float4 v = *(const float4*)(x + i);
    half4_t o;
    o.x = (_Float16)v.x; o.y = (_Float16)v.y; o.z = (_Float16)v.z; o.w = (_Float16)v.w;
    *(half4_t*)(xh + i) = o;
  } else {
    int t = bid - 12288;
    int z = t / 144;
    int r = t % 144;
    int kx = r / 12, ny = r % 12;
    const float* W = (z == 0) ? W0 : (z == 1) ? W1 : W2;
    _Float16* o = WT + (size_t)z * D_DIM * D_DIM;
    int k0 = kx * 64, n0 = ny * 64;
#pragma unroll
    for (int i = 0; i < 16; ++i) {
      int idx = threadIdx.x + i * 256;
      int rr = idx >> 6, cc = idx & 63;
      tile[rr][cc] = (_Float16)W[(size_t)(k0 + rr) * D_DIM + n0 + cc];
    }
    __syncthreads();
#pragma unroll
    for (int i = 0; i < 16; ++i) {
      int idx = threadIdx.x + i * 256;
      int rr = idx >> 6, cc = idx & 63;
      o[(size_t)(n0 + rr) * D_DIM + k0 + cc] = tile[cc][rr];
    }
  }
}

// ============ m97-style 4-wave GEMM core: BM=BN=128, BK=64, SINGLE 32 KB buffer ====
// 256 thr = 4 waves (wr=w>>1, wc=w&1), wave tile 64x64 (4x4 frags, 64 AGPR acc).
// Per K-step: STG (8 global_load_lds) -> __syncthreads -> 16 ds_read_b128 +
// 32 MFMA -> __syncthreads. 3 blocks/CU co-resident; cross-block overlap hides
// the drain (m114/m97 structure; best measured operating point, rounds 13-17).
// Structural note: wave tile is capped at 4x4 (acc=64 AGPR; larger -> >128
// unified regs/wave -> 1 wave/SIMD, fatal per round 11), which fixes LDS
// traffic at 512 B/MFMA; measured ~76% of the 256 B/cy LDS ceiling -> this
// core is near ITS bound. 256^2 deep-pipeline alternatives regressed 3x
// (rounds 15/16/18): 12-tile K-chains never amortize the pipeline fill.
// Granule swizzle u' = u ^ (row&7) (verified conflict-free, rounds 12-17).
template <bool SWAP>
__device__ __forceinline__ void core128(const _Float16* __restrict__ Ag,
                                        const _Float16* __restrict__ Bg,
                                        int lda, int ldb, int nt,
                                        char* lds, float4_t (&acc)[4][4]) {
  const int tid = threadIdx.x;
  const int w = tid >> 6, l = tid & 63;
  const int wr = w >> 1, wc = w & 1;
  const int l15 = l & 15, l4 = l >> 4;

  int sA[4], sB[4], sDst[4];
#pragma unroll
  for (int i = 0; i < 4; ++i) {
    int L = i * 256 + tid;
    int row = L >> 3, u = L & 7;
    int usw = u ^ (row & 7);
    sA[i] = row * lda + usw * 8;
    sB[i] = row * ldb + usw * 8;
    sDst[i] = (i * 256 + (tid & ~63)) * 16;
  }

  int aOff[2][4], bOff[2][4];
#pragma unroll
  for (int ks = 0; ks < 2; ++ks) {
#pragma unroll
    for (int i = 0; i < 4; ++i) {
      int ar = wr * 64 + i * 16 + l15;
      aOff[ks][i] = ar * 128 + (((ks * 4 + l4) ^ (ar & 7)) * 16);
      int br = wc * 64 + i * 16 + l15;
      bOff[ks][i] = 16384 + br * 128 + (((ks * 4 + l4) ^ (br & 7)) * 16);
    }
  }

#pragma unroll 1
  for (int kt = 0; kt < nt; ++kt) {
#pragma unroll
    for (int i = 0; i < 4; ++i)
      GLOAD_LDS16(Ag + (size_t)kt * 64 + sA[i], lds + sDst[i]);
#pragma unroll
    for (int i = 0; i < 4; ++i)
      GLOAD_LDS16(Bg + (size_t)kt * 64 + sB[i], lds + 16384 + sDst[i]);
    __syncthreads();  // drains vmcnt -> tile in LDS for all waves
#pragma unroll
    for (int ks = 0; ks < 2; ++ks) {
      half8_t af[4], bf[4];
#pragma unroll
      for (int ni = 0; ni < 4; ++ni) bf[ni] = *(const half8_t*)(lds + bOff[ks][ni]);
#pragma unroll
      for (int mi = 0; mi < 4; ++mi) af[mi] = *(const half8_t*)(lds + aOff[ks][mi]);
      __builtin_amdgcn_s_setprio(1);
#pragma unroll
      for (int mi = 0; mi < 4; ++mi)
#pragma unroll
        for (int ni = 0; ni < 4; ++ni) {
          if (SWAP)
            acc[mi][ni] = mfma16(bf[ni], af[mi], acc[mi][ni]);
          else
            acc[mi][ni] = mfma16(af[mi], bf[ni], acc[mi][ni]);
        }
      __builtin_amdgcn_s_setprio(0);
    }
    __syncthreads();  // all reads done before next stage overwrites
  }
}

// ---------------- proj: q,k normal; v written directly transposed ----------------
// grid 2304 = 8 x 288 (XCD-bijective). wid = rbg*18 + z*6 + cb. (round-14/17 best)
__global__ __launch_bounds__(256) void proj8_kernel(const _Float16* __restrict__ xh,
                                                    const _Float16* __restrict__ WT,
                                                    _Float16* __restrict__ qkv,
                                                    _Float16* __restrict__ vt) {
  __shared__ __align__(16) char lds[32768];
  const int bid = blockIdx.x;
  const int wid = (bid & 7) * 288 + (bid >> 3);
  const int rbg = wid / 18;
  const int rem = wid % 18;
  const int z = rem / 6;
  const int cb = rem % 6;

  const _Float16* Ag = xh + (size_t)rbg * 128 * D_DIM;
  const _Float16* Bg = WT + (size_t)z * D_DIM * D_DIM + (size_t)cb * 128 * D_DIM;
  float4_t acc[4][4];
#pragma unroll
  for (int a = 0; a < 4; ++a)
#pragma unroll
    for (int b = 0; b < 4; ++b) acc[a][b] = (float4_t){0.f, 0.f, 0.f, 0.f};

  const int tid = threadIdx.x;
  const int w = tid >> 6, l = tid & 63;
  const int wr = w >> 1, wc = w & 1;
  const int l15 = l & 15, l4 = l >> 4;

  if (z < 2) {
    core128<false>(Ag, Bg, D_DIM, D_DIM, 12, lds, acc);
    _Float16* C = qkv + (size_t)z * M_DIM * D_DIM;
#pragma unroll
    for (int mi = 0; mi < 4; ++mi)
#pragma unroll
      for (int ni = 0; ni < 4; ++ni) {
        int col = cb * 128 + wc * 64 + ni * 16 + l15;
#pragma unroll
        for (int j = 0; j < 4; ++j) {
          int row = rbg * 128 + wr * 64 + mi * 16 + l4 * 4 + j;
          C[(size_t)row * D_DIM + col] = (_Float16)acc[mi][ni][j];
        }
      }
  } else {
    core128<true>(Ag, Bg, D_DIM, D_DIM, 12, lds, acc);
    // acc holds transposed tile: out-row = W-row (d), out-col = x-row (s)
#pragma unroll
    for (int mi = 0; mi < 4; ++mi) {
      int scol = rbg * 128 + wr * 64 + mi * 16 + l15;
      int bb = scol >> 12;
      int sl = scol & 4095;
      _Float16* vtb = vt + (size_t)bb * SD;
#pragma unroll
      for (int ni = 0; ni < 4; ++ni) {
#pragma unroll
        for (int j = 0; j < 4; ++j) {
          int drow = cb * 128 + wc * 64 + ni * 16 + l4 * 4 + j;
          vtb[(size_t)drow * S_DIM + sl] = (_Float16)acc[mi][ni][j];
        }
      }
    }
  }
}

// ---------------- gemm1: P = exp(scale*QK^T - 4) causal ----------------
// grid 2112 = 8 x 264. Per z: 528 lower-triangle 128^2 blocks, 4x4-supertiled.
__global__ __launch_bounds__(256) void gemm1_8_kernel(const _Float16* __restrict__ Q,
                                                      const _Float16* __restrict__ K,
                                                      _Float16* __restrict__ P,
                                                      float* __restrict__ rp) {
  __shared__ __align__(16) char lds[32768];
  const float SCALE = 0.036084391824351615f;  // 1/sqrt(768)
  const int bid = blockIdx.x;
  const int wid = (bid & 7) * 264 + (bid >> 3);
  const int z = wid / 528;
  const int t = wid % 528;
  int g = 0;
  while (g < 7 && (8 * (g + 1) * g + 10 * (g + 1)) <= t) ++g;
  int r = t - (8 * g * (g - 1) + 10 * g);
  int rbg, cb;
  if (r < 16 * g) {
    int cbg = r >> 4, wi = r & 15;
    rbg = 4 * g + (wi >> 2);
    cb = 4 * cbg + (wi & 3);
  } else {
    int r2 = r - 16 * g;
    const int ri[10] = {0, 1, 1, 2, 2, 2, 3, 3, 3, 3};
    const int rj[10] = {0, 0, 1, 0, 1, 2, 0, 1, 2, 3};
    rbg = 4 * g + ri[r2];
    cb = 4 * g + rj[r2];
  }

  const _Float16* Ag = Q + (size_t)z * SD + (size_t)rbg * 128 * D_DIM;
  const _Float16* Bg = K + (size_t)z * SD + (size_t)cb * 128 * D_DIM;
  float4_t acc[4][4];
#pragma unroll
  for (int a = 0; a < 4; ++a)
#pragma unroll
    for (int b = 0; b < 4; ++b) acc[a][b] = (float4_t){0.f, 0.f, 0.f, 0.f};
  core128<false>(Ag, Bg, D_DIM, D_DIM, 12, lds, acc);

  const int tid = threadIdx.x;
  const int w = tid >> 6, l = tid & 63;
  const int wr = w >> 1, wc = w & 1;
  const int l15 = l & 15, l4 = l >> 4;
  _Float16* Pz = P + (size_t)z * S_DIM * S_DIM;
  float* rpz = rp + (size_t)z * S_DIM * 64;
#pragma unroll
  for (int mi = 0; mi < 4; ++mi) {
#pragma unroll
    for (int j = 0; j < 4; ++j) {
      int row = rbg * 128 + wr * 64 + mi * 16 + l4 * 4 + j;
      float rs = 0.f;
#pragma unroll
      for (int ni = 0; ni < 4; ++ni) {
        int col = cb * 128 + wc * 64 + ni * 16 + l15;
        float v = (col <= row) ? __expf(acc[mi][ni][j] * SCALE - 4.0f) : 0.f;
        _Float16 ph = (_Float16)v;
        Pz[(size_t)row * S_DIM + col] = ph;
        rs += (float)ph;
      }
#pragma unroll
      for (int d = 1; d < 16; d <<= 1) rs += __shfl_xor(rs, d);
      if (l15 == 0) rpz[(size_t)row * 64 + cb * 2 + wc] = rs;
    }
  }
}

// ---------------- gemm2: out = (P @ VT^T)/rsum — 768 single-job LPT blocks ------
// One job per block; nt = 2(rbg+1); rank g = bid/24 runs rbg = 31-g (LPT list
// scheduling via bid-order backfill). xcd-slot mapping keeps each XCD's 3 VT
// panels (3 MB) L2-resident. rsum computed IN-KERNEL from rp partials.
__global__ __launch_bounds__(256) void gemm2_8_kernel(const _Float16* __restrict__ P,
                                                      const _Float16* __restrict__ VT,
                                                      float* __restrict__ outp,
                                                      const float* __restrict__ rp) {
  __shared__ __align__(16) char lds[32768];
  __shared__ float rsm[128];
  const int bid = blockIdx.x;
  const int g = bid / 24;           // rank: 0 = heaviest
  const int q = bid % 24;
  const int rbg = 31 - g;
  const int xcd = q & 7;
  const int slot = q >> 3;
  const int z = xcd >> 1;
  const int by = (xcd & 1) * 3 + slot;
  const int nt = 2 * (rbg + 1);

  const _Float16* Ag = P + (size_t)z * S_DIM * S_DIM + (size_t)rbg * 128 * S_DIM;
  const _Float16* Bg = VT + (size_t)z * SD + (size_t)by * 128 * S_DIM;
  float4_t acc[4][4];
#pragma unroll
  for (int a = 0; a < 4; ++a)
#pragma unroll
    for (int b = 0; b < 4; ++b) acc[a][b] = (float4_t){0.f, 0.f, 0.f, 0.f};
  core128<false>(Ag, Bg, S_DIM, S_DIM, nt, lds, acc);

  const int tid = threadIdx.x;
  // in-kernel rsum: row partials rp[(z*4096 + rbg*128 + t)*64 + i], i < nt
  if (tid < 128) {
    const float* p = rp + ((size_t)z * S_DIM + (size_t)rbg * 128 + tid) * 64;
    float s = 0.f;
    for (int i = 0; i < nt; ++i) s += p[i];
    rsm[tid] = 1.0f / s;
  }
  __syncthreads();

  const int w = tid >> 6, l = tid & 63;
  const int wr = w >> 1, wc = w & 1;
  const int l15 = l & 15, l4 = l >> 4;
#pragma unroll
  for (int mi = 0; mi < 4; ++mi) {
#pragma unroll
    for (int j = 0; j < 4; ++j) {
      int lrow = wr * 64 + mi * 16 + l4 * 4 + j;  // row within the 128-row block
      int row = rbg * 128 + lrow;                 // batch-local row
      float rinv = rsm[lrow];
#pragma unroll
      for (int ni = 0; ni < 4; ++ni) {
        int col = by * 128 + wc * 64 + ni * 16 + l15;
        outp[(size_t)z * SD + (size_t)row * D_DIM + col] = acc[mi][ni][j] * rinv;
      }
    }
  }
}

extern "C" void kernel_launch(void* const* d_in, const int* in_sizes, int n_in,
                              void* d_out, int out_size, void* d_ws, size_t ws_size,
                              hipStream_t stream) {
  const float* x = (const float*)d_in[0];
  const float* Wq = (const float*)d_in[1];
  const float* Wk = (const float*)d_in[2];
  const float* Wv = (const float*)d_in[3];
  float* out = (float*)d_out;
  char* ws = (char*)d_ws;

  const size_t XH_B = (size_t)M_DIM * D_DIM * 2;      // 25,165,824
  const size_t QKV_B = 3 * XH_B;                      // 75,497,472
  const size_t VT_B = XH_B;                           // 25,165,824
  const size_t WT_B = (size_t)3 * D_DIM * D_DIM * 2;  // 3,538,944
  const size_t BASE_END = XH_B + QKV_B + VT_B + WT_B; // 129,368,064

  _Float16* xh = (_Float16*)ws;
  _Float16* qkv = (_Float16*)(ws + XH_B);
  _Float16* Q = qkv;
  _Float16* K = qkv + (size_t)M_DIM * D_DIM;
  _Float16* vt = (_Float16*)(ws + XH_B + QKV_B);
  _Float16* wt = (_Float16*)(ws + XH_B + QKV_B + VT_B);

  // tier-A layout (rounds 4-18 prove ws_size >= 267,845,632)
  float* rp = (float*)(ws + BASE_END);                        // 4 MB
  _Float16* P = (_Float16*)(ws + BASE_END + (size_t)4259840); // 134 MB

  prep_kernel<<<dim3(12720), dim3(256), 0, stream>>>(x, Wq, Wk, Wv, xh, wt);
  proj8_kernel<<<dim3(2304), dim3(256), 0, stream>>>(xh, wt, qkv, vt);
  gemm1_8_kernel<<<dim3(2112), dim3(256), 0, stream>>>(Q, K, P, rp);
  gemm2_8_kernel<<<dim3(768), dim3(256), 0, stream>>>(P, vt, out, rp);
}